// Round 8
// baseline (179.415 us; speedup 1.0000x reference)
//
#include <hip/hip_runtime.h>
#include <hip/hip_bf16.h>
#include <math.h>

#define BB 8
#define TT 2048
#define CC 1024
#define HH 64
#define BT (BB * TT)   // 16384 rows

typedef __attribute__((ext_vector_type(8))) short short8;   // bf16 x8 MFMA frag
typedef __attribute__((ext_vector_type(4))) float floatx4;  // MFMA acc

static __device__ inline ushort f2bf(float f) {
    __hip_bfloat16 h = __float2bfloat16(f);
    return *reinterpret_cast<ushort*>(&h);
}
static __device__ inline unsigned int f2bf2(float lo, float hi) {
    __hip_bfloat162 h = __float22bfloat162_rn(make_float2(lo, hi));
    return *reinterpret_cast<unsigned int*>(&h);
}
static __device__ inline float bf2f(ushort u) {
    union { unsigned int i; float f; } c;
    c.i = ((unsigned int)u) << 16;
    return c.f;
}

// ---------------------------------------------------------------------------
// Kernel 0: W prep (coalesced).  W[k][n] fp32 -> WbT[m][n][k] bf16.
// ---------------------------------------------------------------------------
__global__ __launch_bounds__(256) void wprep_kernel(
    const float* __restrict__ Wq, const float* __restrict__ Wk,
    const float* __restrict__ Wv, ushort* __restrict__ WbT)
{
    __shared__ float ws_[64 * 65];
    const int m  = blockIdx.x >> 4;          // 0..2
    const int kb = (blockIdx.x & 15) * 64;   // 0..960
    const float* W = (m == 0) ? Wq : (m == 1) ? Wk : Wv;
    const int t  = threadIdx.x;
    const int lr = t >> 4, lc = (t & 15) * 4;
    #pragma unroll
    for (int i = 0; i < 4; ++i) {
        const int row = lr + i * 16;
        float4 v = *(const float4*)&W[(size_t)(kb + row) * HH + lc];
        ws_[row * 65 + lc + 0] = v.x; ws_[row * 65 + lc + 1] = v.y;
        ws_[row * 65 + lc + 2] = v.z; ws_[row * 65 + lc + 3] = v.w;
    }
    __syncthreads();
    const int n = t & 63, kseg = t >> 6;     // kseg 0..3 -> 16 k each
    union { ushort s[16]; uint4 q[2]; } u;
    #pragma unroll
    for (int j = 0; j < 16; ++j)
        u.s[j] = f2bf(ws_[(kseg * 16 + j) * 65 + n]);
    ushort* dst = &WbT[(size_t)(m * 64 + n) * 1024 + kb + kseg * 16];
    *(uint4*)&dst[0] = u.q[0];
    *(uint4*)&dst[8] = u.q[1];
}

// ---------------------------------------------------------------------------
// Kernel 1: QKV transposed-MFMA (out^T = mfma(A=W^T, B=x^T)), occupancy-first.
// Round-6 post-mortem: 2 blocks/CU & sunk prefetches -> 666 GB/s latency wall
// (Little's law: need ~22 KB in flight/CU).  Fix: 16 rows/block, 4 waves x
// 3 col-tiles, grid 1024 = 4 blocks/CU = 16 waves/CU, ~80 VGPR.  Loads are
// issued per-iter and TLP (16 drifting waves, no barriers) hides latency.
// MFMA K-order per output element identical -> bit-exact (absmax canary).
// ---------------------------------------------------------------------------
__global__ __launch_bounds__(256, 4) void qkv_kernel(
    const float* __restrict__ x, const ushort* __restrict__ WbT,
    ushort* __restrict__ qb, ushort* __restrict__ kbS, ushort* __restrict__ vS)
{
    const int t    = threadIdx.x;
    const int w    = t >> 6;
    const int lane = t & 63;
    const int l16  = lane & 15;
    const int quad = lane >> 4;

    const int rows0 = blockIdx.x * 16;   // this block's 16 x-rows
    const int ct0   = w * 3;             // this wave's 3 col-tiles

    // per-lane x pointer: row = rows0 + l16, k base = quad*8
    const float* xr = &x[(size_t)(rows0 + l16) * CC + quad * 8];
    const ushort* wb = &WbT[(size_t)l16 * 1024 + quad * 8];

    floatx4 acc[3];
    #pragma unroll
    for (int c = 0; c < 3; ++c) acc[c] = (floatx4){0.f, 0.f, 0.f, 0.f};

    // x current-iter regs (depth-1 pipeline)
    float4 xc[2][2];
    #pragma unroll
    for (int p = 0; p < 2; ++p) {
        xc[p][0] = *(const float4*)&xr[p * 32 + 0];
        xc[p][1] = *(const float4*)&xr[p * 32 + 4];
    }

    #pragma unroll 4
    for (int it = 0; it < 16; ++it) {
        // W frags for this iter (at-use; TLP hides the L2 latency)
        short8 af[2][3];
        #pragma unroll
        for (int p = 0; p < 2; ++p)
            #pragma unroll
            for (int c = 0; c < 3; ++c)
                af[p][c] = *(const short8*)&wb[(size_t)(ct0 + c) * 16384
                                               + it * 64 + p * 32];

        // convert current x -> B-frags
        short8 bx[2];
        #pragma unroll
        for (int p = 0; p < 2; ++p) {
            union { unsigned int u[4]; short8 s; } cv;
            cv.u[0] = f2bf2(xc[p][0].x, xc[p][0].y);
            cv.u[1] = f2bf2(xc[p][0].z, xc[p][0].w);
            cv.u[2] = f2bf2(xc[p][1].x, xc[p][1].y);
            cv.u[3] = f2bf2(xc[p][1].z, xc[p][1].w);
            bx[p] = cv.s;
        }

        // prefetch x for it+1
        if (it + 1 < 16) {
            #pragma unroll
            for (int p = 0; p < 2; ++p) {
                xc[p][0] = *(const float4*)&xr[(it + 1) * 64 + p * 32 + 0];
                xc[p][1] = *(const float4*)&xr[(it + 1) * 64 + p * 32 + 4];
            }
        }

        __builtin_amdgcn_s_setprio(1);
        #pragma unroll
        for (int p = 0; p < 2; ++p)
            #pragma unroll
            for (int c = 0; c < 3; ++c)
                acc[c] = __builtin_amdgcn_mfma_f32_16x16x32_bf16(af[p][c], bx[p], acc[c], 0, 0, 0);
        __builtin_amdgcn_s_setprio(0);
    }

    // ---- epilogue: D row = h-sub (quad*4+reg), col = x-row (l16) ----
    const size_t tile = (size_t)(rows0 >> 6) * 4096;
    #pragma unroll
    for (int c = 0; c < 3; ++c) {
        const int ct    = ct0 + c;
        const int mtype = ct >> 2;
        const int nn    = ct & 3;
        if (mtype == 0) {                       // q: row-major [row][h], /8 folded
            uint2 u;
            u.x = f2bf2(acc[c][0] * 0.125f, acc[c][1] * 0.125f);
            u.y = f2bf2(acc[c][2] * 0.125f, acc[c][3] * 0.125f);
            *(uint2*)&qb[(size_t)(rows0 + l16) * HH + nn * 16 + quad * 4] = u;
        } else if (mtype == 1) {                // K swizzled (B-frag order)
            const int ckey  = (rows0 >> 4) & 3;
            const int p     = nn >> 1;
            const int quadP = (nn * 2 + (quad >> 1)) & 3;
            const int j0    = (quad & 1) * 4;
            uint2 u;
            u.x = f2bf2(acc[c][0], acc[c][1]);
            u.y = f2bf2(acc[c][2], acc[c][3]);
            *(uint2*)&kbS[tile + (size_t)((ckey * 2 + p) * 64 + quadP * 16 + l16) * 8 + j0] = u;
        } else {                                // V swizzled (B-frag order)
            const int pv = (rows0 >> 5) & 1;
            const int qv = ((rows0 >> 4) & 1) * 2 + (l16 >> 3);
            const int jv = l16 & 7;
            #pragma unroll
            for (int reg = 0; reg < 4; ++reg)
                vS[tile + (size_t)((nn * 2 + pv) * 64 + qv * 16 + quad * 4 + reg) * 8 + jv]
                    = f2bf(acc[c][reg]);
        }
    }
}

// ---------------------------------------------------------------------------
// Kernel 2: split-K MFMA flash attention (barrier-free, swapped QK^T,
// transposed packed Opart).  Unchanged this round.
// ---------------------------------------------------------------------------
__global__ __launch_bounds__(256) void attn_kernel(
    const ushort* __restrict__ qb, const ushort* __restrict__ kbS,
    const ushort* __restrict__ vS, ushort* __restrict__ Opart,
    float* __restrict__ ml)
{
    __shared__ __align__(16) ushort P[4][16 * 72];   // per-wave P tile

    const int t    = threadIdx.x;
    const int w    = t >> 6;
    const int lane = t & 63;
    const int l16  = lane & 15;
    const int quad = lane >> 4;

    const int b   = blockIdx.x & 7;
    const int idx = blockIdx.x >> 3;   // 0..79, heavy-first
    int qt, part, np;
    if (idx < 32)      { qt = 31 - (idx >> 2); part = idx & 3; np = 4; }
    else if (idx < 56) { const int u = idx - 32; const int g = u / 3;
                         qt = 23 - g; part = u - g * 3; np = 3; }
    else if (idx < 72) { const int u = idx - 56; qt = 15 - (u >> 1); part = u & 1; np = 2; }
    else               { qt = 7 - (idx - 72); part = 0; np = 1; }
    const int ntiles = qt + 1;
    const int ktb = (part * ntiles) / np;
    const int kte = ((part + 1) * ntiles) / np;

    const ushort* ktile0 = kbS + (size_t)(b * 32) * 4096;
    const ushort* vtile0 = vS  + (size_t)(b * 32) * 4096;

    // Q frags (B-operand of swapped QK^T; B-frag lane map == A-frag map)
    short8 qf[2];
    {
        const ushort* qrow = qb + ((size_t)b * TT + qt * 64 + w * 16) * HH;
        qf[0] = *(const short8*)&qrow[l16 * HH + quad * 8];
        qf[1] = *(const short8*)&qrow[l16 * HH + 32 + quad * 8];
    }
    short8 ones;
    #pragma unroll
    for (int i = 0; i < 8; ++i) ones[i] = (short)0x3F80;   // bf16 1.0

    floatx4 o[4], osum;
    #pragma unroll
    for (int c = 0; c < 4; ++c) o[c] = (floatx4){0.f, 0.f, 0.f, 0.f};
    osum = (floatx4){0.f, 0.f, 0.f, 0.f};

    ushort* Pw = &P[w][0];

    for (int kt = ktb; kt < kte; ++kt) {
        const ushort* kg = ktile0 + (size_t)kt * 4096;
        const ushort* vg = vtile0 + (size_t)kt * 4096;

        // ---- K frags from global (L2-hit, frag-ordered) ----
        short8 kf[4][2];
        #pragma unroll
        for (int c = 0; c < 4; ++c)
            #pragma unroll
            for (int p = 0; p < 2; ++p)
                kf[c][p] = *(const short8*)&kg[(size_t)(((c * 2 + p) * 64) + lane) * 8];

        // ---- S^T = K Q^T (operand-swapped): row=key chunk, col=q ----
        floatx4 s[4];
        #pragma unroll
        for (int c = 0; c < 4; ++c) s[c] = (floatx4){0.f, 0.f, 0.f, 0.f};
        __builtin_amdgcn_s_setprio(1);
        #pragma unroll
        for (int c = 0; c < 4; ++c)
            #pragma unroll
            for (int p = 0; p < 2; ++p)
                s[c] = __builtin_amdgcn_mfma_f32_16x16x32_bf16(kf[c][p], qf[p], s[c], 0, 0, 0);
        __builtin_amdgcn_s_setprio(0);

        // ---- V frags (issued while exp/P path runs) ----
        short8 vf[4][2];
        #pragma unroll
        for (int c = 0; c < 4; ++c)
            #pragma unroll
            for (int p = 0; p < 2; ++p)
                vf[c][p] = *(const short8*)&vg[(size_t)(((c * 2 + p) * 64) + lane) * 8];

        // ---- causal mask (roles swapped: key from reg, q from l16) ----
        if (kt == ntiles - 1) {
            const int key0 = kt * 64 + quad * 4;
            const int qrow = qt * 64 + w * 16 + l16;
            #pragma unroll
            for (int c = 0; c < 4; ++c)
                #pragma unroll
                for (int reg = 0; reg < 4; ++reg)
                    if (key0 + c * 16 + reg > qrow) s[c][reg] = -1e30f;
        }

        // ---- P = exp(s^T) -> packed bf16 -> LDS row q=l16, keys contiguous ----
        #pragma unroll
        for (int c = 0; c < 4; ++c) {
            uint2 u;
            u.x = f2bf2(__expf(s[c][0]), __expf(s[c][1]));
            u.y = f2bf2(__expf(s[c][2]), __expf(s[c][3]));
            *(uint2*)&Pw[l16 * 72 + c * 16 + quad * 4] = u;
        }

        short8 pf[2];
        pf[0] = *(const short8*)&Pw[l16 * 72 + quad * 8];
        pf[1] = *(const short8*)&Pw[l16 * 72 + 32 + quad * 8];

        // ---- O += P V ; l += P * ones ----
        __builtin_amdgcn_s_setprio(1);
        #pragma unroll
        for (int p = 0; p < 2; ++p) {
            #pragma unroll
            for (int c = 0; c < 4; ++c)
                o[c] = __builtin_amdgcn_mfma_f32_16x16x32_bf16(pf[p], vf[c][p], o[c], 0, 0, 0);
            osum = __builtin_amdgcn_mfma_f32_16x16x32_bf16(pf[p], ones, osum, 0, 0, 0);
        }
        __builtin_amdgcn_s_setprio(0);
    }

    // ---- write partial TRANSPOSED: Opart[unit][col][row], packed b64 ----
    const size_t ub = (size_t)blockIdx.x * 4096;
    const int rbase = w * 16 + quad * 4;
    #pragma unroll
    for (int c = 0; c < 4; ++c) {
        uint2 u;
        u.x = f2bf2(o[c][0], o[c][1]);
        u.y = f2bf2(o[c][2], o[c][3]);
        *(uint2*)&Opart[ub + (size_t)(c * 16 + l16) * 64 + rbase] = u;
    }
    if (l16 == 0) {
        #pragma unroll
        for (int reg = 0; reg < 4; ++reg)
            ml[(size_t)blockIdx.x * 64 + rbase + reg] = osum[reg];
    }
}

// ---------------------------------------------------------------------------
// Kernel 3: merge partials (transposed Opart).  out = (sum O_p) / (sum l_p).
// ---------------------------------------------------------------------------
__global__ __launch_bounds__(256) void merge_kernel(
    const ushort* __restrict__ Opart, const float* __restrict__ ml,
    float* __restrict__ out)
{
    const int t    = threadIdx.x;
    const int gw   = blockIdx.x * 4 + (t >> 6);   // 0..2047
    const int lane = t & 63;                      // = output col
    const int b    = gw >> 8;
    const int v    = gw & 255;
    const int qt   = v >> 3;
    const int oct  = v & 7;

    int base, np;
    if (qt >= 24)      { base = (31 - qt) * 4;      np = 4; }
    else if (qt >= 16) { base = 32 + (23 - qt) * 3; np = 3; }
    else if (qt >= 8)  { base = 56 + (15 - qt) * 2; np = 2; }
    else               { base = 72 + (7 - qt);      np = 1; }

    float* obase = out + ((size_t)b * TT + qt * 64) * HH;

    #pragma unroll
    for (int rg = 0; rg < 2; ++rg) {
        const int row0 = oct * 8 + rg * 4;
        float dx = 0.f, dy = 0.f, dz = 0.f, dw = 0.f;
        float ax = 0.f, ay = 0.f, az = 0.f, aw = 0.f;
        for (int p = 0; p < np; ++p) {
            const int unit = (base + p) * 8 + b;
            float4 d = *(const float4*)&ml[(size_t)unit * 64 + row0];
            dx += d.x; dy += d.y; dz += d.z; dw += d.w;
            ushort4 ov = *(const ushort4*)&Opart[(size_t)unit * 4096 + lane * 64 + row0];
            ax += bf2f(ov.x); ay += bf2f(ov.y); az += bf2f(ov.z); aw += bf2f(ov.w);
        }
        obase[(size_t)(row0 + 0) * HH + lane] = ax / dx;
        obase[(size_t)(row0 + 1) * HH + lane] = ay / dy;
        obase[(size_t)(row0 + 2) * HH + lane] = az / dz;
        obase[(size_t)(row0 + 3) * HH + lane] = aw / dw;
    }
}

// ---------------------------------------------------------------------------
extern "C" void kernel_launch(void* const* d_in, const int* in_sizes, int n_in,
                              void* d_out, int out_size, void* d_ws, size_t ws_size,
                              hipStream_t stream)
{
    (void)in_sizes; (void)n_in; (void)out_size; (void)ws_size;
    const float* x  = (const float*)d_in[0];
    const float* Wq = (const float*)d_in[1];
    const float* Wk = (const float*)d_in[2];
    const float* Wv = (const float*)d_in[3];
    float* outp = (float*)d_out;

    // ws: WbT 384K | qb 2M | kbS 2M | vS 2M | Opart 5.24M | ml 160K (~11.8 MB)
    char* base = (char*)d_ws;
    ushort* WbT   = (ushort*)(base);
    ushort* qbuf  = (ushort*)(base + 393216);
    ushort* kbS   = qbuf + (size_t)BT * HH;
    ushort* vSb   = kbS + (size_t)BT * HH;
    ushort* Opart = vSb + (size_t)BT * HH;
    float*  ml    = (float*)((char*)Opart + (size_t)640 * 4096 * 2);

    wprep_kernel<<<dim3(48),   256, 0, stream>>>(Wq, Wk, Wv, WbT);
    qkv_kernel  <<<dim3(1024), 256, 0, stream>>>(x, WbT, qbuf, kbS, vSb);
    attn_kernel <<<dim3(640),  256, 0, stream>>>(qbuf, kbS, vSb, Opart, ml);
    merge_kernel<<<dim3(512),  256, 0, stream>>>(Opart, ml, outp);
}

// Round 9
// 142.541 us; speedup vs baseline: 1.2587x; 1.2587x over previous
//
#include <hip/hip_runtime.h>
#include <hip/hip_bf16.h>
#include <math.h>

#define BB 8
#define TT 2048
#define CC 1024
#define HH 64
#define BT (BB * TT)   // 16384 rows

typedef __attribute__((ext_vector_type(8))) short short8;   // bf16 x8 MFMA frag
typedef __attribute__((ext_vector_type(4))) float floatx4;  // MFMA acc

static __device__ inline ushort f2bf(float f) {
    __hip_bfloat16 h = __float2bfloat16(f);
    return *reinterpret_cast<ushort*>(&h);
}
static __device__ inline unsigned int f2bf2(float lo, float hi) {
    __hip_bfloat162 h = __float22bfloat162_rn(make_float2(lo, hi));
    return *reinterpret_cast<unsigned int*>(&h);
}
static __device__ inline float bf2f(ushort u) {
    union { unsigned int i; float f; } c;
    c.i = ((unsigned int)u) << 16;
    return c.f;
}
// Barrier that waits ONLY on LDS ops: VMEM prefetches (x, WbT) stay in
// flight across it (T4 counted-wait principle).
static __device__ inline void lds_barrier() {
    asm volatile("s_waitcnt lgkmcnt(0)" ::: "memory");
    __builtin_amdgcn_s_barrier();
}

// ---------------------------------------------------------------------------
// Kernel 0: W prep (coalesced).  W[k][n] fp32 -> WbT[m][n][k] bf16.
// ---------------------------------------------------------------------------
__global__ __launch_bounds__(256) void wprep_kernel(
    const float* __restrict__ Wq, const float* __restrict__ Wk,
    const float* __restrict__ Wv, ushort* __restrict__ WbT)
{
    __shared__ float ws_[64 * 65];
    const int m  = blockIdx.x >> 4;          // 0..2
    const int kb = (blockIdx.x & 15) * 64;   // 0..960
    const float* W = (m == 0) ? Wq : (m == 1) ? Wk : Wv;
    const int t  = threadIdx.x;
    const int lr = t >> 4, lc = (t & 15) * 4;
    #pragma unroll
    for (int i = 0; i < 4; ++i) {
        const int row = lr + i * 16;
        float4 v = *(const float4*)&W[(size_t)(kb + row) * HH + lc];
        ws_[row * 65 + lc + 0] = v.x; ws_[row * 65 + lc + 1] = v.y;
        ws_[row * 65 + lc + 2] = v.z; ws_[row * 65 + lc + 3] = v.w;
    }
    __syncthreads();
    const int n = t & 63, kseg = t >> 6;     // kseg 0..3 -> 16 k each
    union { ushort s[16]; uint4 q[2]; } u;
    #pragma unroll
    for (int j = 0; j < 16; ++j)
        u.s[j] = f2bf(ws_[(kseg * 16 + j) * 65 + n]);
    ushort* dst = &WbT[(size_t)(m * 64 + n) * 1024 + kb + kseg * 16];
    *(uint4*)&dst[0] = u.q[0];
    *(uint4*)&dst[8] = u.q[1];
}

// ---------------------------------------------------------------------------
// Kernel 1: QKV — round-5 version verbatim (measured best, ~38 µs):
// 32-row staged structure, lgkm-only barrier, depth-2 x prefetch,
// depth-1 WbT prefetch.
// ---------------------------------------------------------------------------
__global__ __launch_bounds__(256) void qkv_kernel(
    const float* __restrict__ x, const ushort* __restrict__ WbT,
    ushort* __restrict__ qb, ushort* __restrict__ kbS, ushort* __restrict__ vS)
{
    __shared__ __align__(16) ushort As[2][256 * 8];   // frag-major

    const int row0 = blockIdx.x * 32;
    const int t    = threadIdx.x;
    const int w    = t >> 6;
    const int lane = t & 63;
    const int l16  = lane & 15;
    const int quad = lane >> 4;
    const int ct0  = w * 3;

    const int srow = t >> 3, sseg = t & 7;
    const int slot = (((sseg >> 2) * 2 + (srow >> 4)) * 16 + (srow & 15)) * 4 + (sseg & 3);
    const float* xsrc = &x[(size_t)(row0 + srow) * CC + sseg * 8];

    floatx4 acc[2][3];
    #pragma unroll
    for (int mt = 0; mt < 2; ++mt)
        #pragma unroll
        for (int c = 0; c < 3; ++c) acc[mt][c] = (floatx4){0.f, 0.f, 0.f, 0.f};

    // ---- depth-2 register prefetch of x ----
    float4 xa0 = *(const float4*)&xsrc[0];
    float4 xb0 = *(const float4*)&xsrc[4];
    float4 xa1 = *(const float4*)&xsrc[64];
    float4 xb1 = *(const float4*)&xsrc[68];

    short8 bfr[2][3];
    #pragma unroll
    for (int p = 0; p < 2; ++p)
        #pragma unroll
        for (int c = 0; c < 3; ++c)
            bfr[p][c] = *(const short8*)&WbT[(size_t)((ct0 + c) * 16 + l16) * 1024
                                             + p * 32 + quad * 8];

    auto body = [&](int it, float4& xa, float4& xb) {
        uint4 uq;
        uq.x = f2bf2(xa.x, xa.y); uq.y = f2bf2(xa.z, xa.w);
        uq.z = f2bf2(xb.x, xb.y); uq.w = f2bf2(xb.z, xb.w);
        *(uint4*)&As[it & 1][slot * 8] = uq;
        lds_barrier();                        // lgkm-only: VMEM stays in flight

        if (it + 2 < 16) {                    // x prefetch, 2 iters ahead
            xa = *(const float4*)&xsrc[(it + 2) * 64 + 0];
            xb = *(const float4*)&xsrc[(it + 2) * 64 + 4];
        }
        short8 bnx[2][3];
        if (it < 15) {                        // WbT prefetch, 1 iter ahead
            const int kn = (it + 1) * 64;
            #pragma unroll
            for (int p = 0; p < 2; ++p)
                #pragma unroll
                for (int c = 0; c < 3; ++c)
                    bnx[p][c] = *(const short8*)&WbT[(size_t)((ct0 + c) * 16 + l16) * 1024
                                                     + kn + p * 32 + quad * 8];
        }

        short8 a0 = *(const short8*)&As[it & 1][(size_t)((0 * 2 + 0) * 64 + l16 * 4 + quad) * 8 + 0];
        short8 a1 = *(const short8*)&As[it & 1][(size_t)((0 * 2 + 1) * 64 + l16 * 4 + quad) * 8 + 0];
        short8 a2 = *(const short8*)&As[it & 1][(size_t)((1 * 2 + 0) * 64 + l16 * 4 + quad) * 8 + 0];
        short8 a3 = *(const short8*)&As[it & 1][(size_t)((1 * 2 + 1) * 64 + l16 * 4 + quad) * 8 + 0];

        __builtin_amdgcn_s_setprio(1);
        #pragma unroll
        for (int c = 0; c < 3; ++c) {
            acc[0][c] = __builtin_amdgcn_mfma_f32_16x16x32_bf16(a0, bfr[0][c], acc[0][c], 0, 0, 0);
            acc[1][c] = __builtin_amdgcn_mfma_f32_16x16x32_bf16(a1, bfr[0][c], acc[1][c], 0, 0, 0);
            acc[0][c] = __builtin_amdgcn_mfma_f32_16x16x32_bf16(a2, bfr[1][c], acc[0][c], 0, 0, 0);
            acc[1][c] = __builtin_amdgcn_mfma_f32_16x16x32_bf16(a3, bfr[1][c], acc[1][c], 0, 0, 0);
        }
        __builtin_amdgcn_s_setprio(0);

        #pragma unroll
        for (int p = 0; p < 2; ++p)
            #pragma unroll
            for (int c = 0; c < 3; ++c)
                bfr[p][c] = bnx[p][c];
    };

    for (int it2 = 0; it2 < 16; it2 += 2) {
        body(it2 + 0, xa0, xb0);
        body(it2 + 1, xa1, xb1);
    }

    // ---- epilogue ----
    const int half = (row0 >> 5) & 1;              // which 32-row half of the 64-tile
    const size_t tile = (size_t)(row0 >> 6) * 4096;
    #pragma unroll
    for (int c = 0; c < 3; ++c) {
        const int ct    = ct0 + c;
        const int mtype = ct >> 2;
        const int n0    = (ct & 3) * 16;
        #pragma unroll
        for (int mt = 0; mt < 2; ++mt) {
            const int row = row0 + mt * 16 + quad * 4;
            if (mtype == 0) {                       // q: row-major, /8 folded
                #pragma unroll
                for (int reg = 0; reg < 4; ++reg)
                    qb[(size_t)(row + reg) * HH + n0 + l16] = f2bf(acc[mt][c][reg] * 0.125f);
            } else if (mtype == 1) {                // K swizzled (B-frag order)
                const int cP    = half * 2 + mt;
                const int pP    = (ct & 3) >> 1;
                const int quadP = ((ct & 3) * 2 + (l16 >> 3)) & 3;
                const int jP    = l16 & 7;
                const int ub    = (cP * 2 + pP) * 64 + quadP * 16;
                #pragma unroll
                for (int reg = 0; reg < 4; ++reg)
                    kbS[tile + (size_t)(ub + quad * 4 + reg) * 8 + jP] = f2bf(acc[mt][c][reg]);
            } else {                                // V swizzled (B-frag order)
                const int cp2 = (ct & 3) * 2 + half;   // c'*2 + p'
                #pragma unroll
                for (int reg = 0; reg < 4; ++reg) {
                    const int rq    = quad * 4 + reg;
                    const int quadP = mt * 2 + (rq >> 3);
                    vS[tile + (size_t)(cp2 * 64 + quadP * 16 + l16) * 8 + (rq & 7)] = f2bf(acc[mt][c][reg]);
                }
            }
        }
    }
}

// ---------------------------------------------------------------------------
// Kernel 2: split-K MFMA flash attention.  THIS round: split-K parallelism
// DOUBLED — np = {8,6,4,2} by qt quartile -> 1280 blocks = 5 blocks/CU =
// 20 waves/CU.  Per-block kt-iterations halve (max 4), so the per-iter
// serial chain (K L2-load -> QK^T -> exp/LDS -> PV) is covered by CU-level
// wave interleave.  Everything else unchanged.
// ---------------------------------------------------------------------------
__global__ __launch_bounds__(256) void attn_kernel(
    const ushort* __restrict__ qb, const ushort* __restrict__ kbS,
    const ushort* __restrict__ vS, ushort* __restrict__ Opart,
    float* __restrict__ ml)
{
    __shared__ __align__(16) ushort P[4][16 * 72];   // per-wave P tile

    const int t    = threadIdx.x;
    const int w    = t >> 6;
    const int lane = t & 63;
    const int l16  = lane & 15;
    const int quad = lane >> 4;

    const int b   = blockIdx.x & 7;
    const int idx = blockIdx.x >> 3;   // 0..159, heavy-first
    int qt, part, np;
    if (idx < 64)       { qt = 31 - (idx >> 3); part = idx & 7; np = 8; }
    else if (idx < 112) { const int u = idx - 64; const int g = u / 6;
                          qt = 23 - g; part = u - g * 6; np = 6; }
    else if (idx < 144) { const int u = idx - 112; qt = 15 - (u >> 2); part = u & 3; np = 4; }
    else                { const int u = idx - 144; qt = 7 - (u >> 1); part = u & 1; np = 2; }
    const int ntiles = qt + 1;
    const int ktb = (part * ntiles) / np;
    const int kte = ((part + 1) * ntiles) / np;

    const ushort* ktile0 = kbS + (size_t)(b * 32) * 4096;
    const ushort* vtile0 = vS  + (size_t)(b * 32) * 4096;

    // Q frags (B-operand of swapped QK^T; B-frag lane map == A-frag map)
    short8 qf[2];
    {
        const ushort* qrow = qb + ((size_t)b * TT + qt * 64 + w * 16) * HH;
        qf[0] = *(const short8*)&qrow[l16 * HH + quad * 8];
        qf[1] = *(const short8*)&qrow[l16 * HH + 32 + quad * 8];
    }
    short8 ones;
    #pragma unroll
    for (int i = 0; i < 8; ++i) ones[i] = (short)0x3F80;   // bf16 1.0

    floatx4 o[4], osum;
    #pragma unroll
    for (int c = 0; c < 4; ++c) o[c] = (floatx4){0.f, 0.f, 0.f, 0.f};
    osum = (floatx4){0.f, 0.f, 0.f, 0.f};

    ushort* Pw = &P[w][0];

    for (int kt = ktb; kt < kte; ++kt) {
        const ushort* kg = ktile0 + (size_t)kt * 4096;
        const ushort* vg = vtile0 + (size_t)kt * 4096;

        // ---- K frags from global (L2-hit, frag-ordered) ----
        short8 kf[4][2];
        #pragma unroll
        for (int c = 0; c < 4; ++c)
            #pragma unroll
            for (int p = 0; p < 2; ++p)
                kf[c][p] = *(const short8*)&kg[(size_t)(((c * 2 + p) * 64) + lane) * 8];

        // ---- S^T = K Q^T (operand-swapped): row=key chunk, col=q ----
        floatx4 s[4];
        #pragma unroll
        for (int c = 0; c < 4; ++c) s[c] = (floatx4){0.f, 0.f, 0.f, 0.f};
        __builtin_amdgcn_s_setprio(1);
        #pragma unroll
        for (int c = 0; c < 4; ++c)
            #pragma unroll
            for (int p = 0; p < 2; ++p)
                s[c] = __builtin_amdgcn_mfma_f32_16x16x32_bf16(kf[c][p], qf[p], s[c], 0, 0, 0);
        __builtin_amdgcn_s_setprio(0);

        // ---- V frags (issued while exp/P path runs) ----
        short8 vf[4][2];
        #pragma unroll
        for (int c = 0; c < 4; ++c)
            #pragma unroll
            for (int p = 0; p < 2; ++p)
                vf[c][p] = *(const short8*)&vg[(size_t)(((c * 2 + p) * 64) + lane) * 8];

        // ---- causal mask (roles swapped: key from reg, q from l16) ----
        if (kt == ntiles - 1) {
            const int key0 = kt * 64 + quad * 4;
            const int qrow = qt * 64 + w * 16 + l16;
            #pragma unroll
            for (int c = 0; c < 4; ++c)
                #pragma unroll
                for (int reg = 0; reg < 4; ++reg)
                    if (key0 + c * 16 + reg > qrow) s[c][reg] = -1e30f;
        }

        // ---- P = exp(s^T) -> packed bf16 -> LDS row q=l16, keys contiguous ----
        #pragma unroll
        for (int c = 0; c < 4; ++c) {
            uint2 u;
            u.x = f2bf2(__expf(s[c][0]), __expf(s[c][1]));
            u.y = f2bf2(__expf(s[c][2]), __expf(s[c][3]));
            *(uint2*)&Pw[l16 * 72 + c * 16 + quad * 4] = u;
        }

        short8 pf[2];
        pf[0] = *(const short8*)&Pw[l16 * 72 + quad * 8];
        pf[1] = *(const short8*)&Pw[l16 * 72 + 32 + quad * 8];

        // ---- O += P V ; l += P * ones ----
        __builtin_amdgcn_s_setprio(1);
        #pragma unroll
        for (int p = 0; p < 2; ++p) {
            #pragma unroll
            for (int c = 0; c < 4; ++c)
                o[c] = __builtin_amdgcn_mfma_f32_16x16x32_bf16(pf[p], vf[c][p], o[c], 0, 0, 0);
            osum = __builtin_amdgcn_mfma_f32_16x16x32_bf16(pf[p], ones, osum, 0, 0, 0);
        }
        __builtin_amdgcn_s_setprio(0);
    }

    // ---- write partial TRANSPOSED: Opart[unit][col][row], packed b64 ----
    const size_t ub = (size_t)blockIdx.x * 4096;
    const int rbase = w * 16 + quad * 4;
    #pragma unroll
    for (int c = 0; c < 4; ++c) {
        uint2 u;
        u.x = f2bf2(o[c][0], o[c][1]);
        u.y = f2bf2(o[c][2], o[c][3]);
        *(uint2*)&Opart[ub + (size_t)(c * 16 + l16) * 64 + rbase] = u;
    }
    if (l16 == 0) {
        #pragma unroll
        for (int reg = 0; reg < 4; ++reg)
            ml[(size_t)blockIdx.x * 64 + rbase + reg] = osum[reg];
    }
}

// ---------------------------------------------------------------------------
// Kernel 3: merge partials (transposed Opart, np<=8).  16B row loads.
// ---------------------------------------------------------------------------
__global__ __launch_bounds__(256) void merge_kernel(
    const ushort* __restrict__ Opart, const float* __restrict__ ml,
    float* __restrict__ out)
{
    const int t    = threadIdx.x;
    const int gw   = blockIdx.x * 4 + (t >> 6);   // 0..2047
    const int lane = t & 63;                      // = output col
    const int b    = gw >> 8;
    const int v    = gw & 255;
    const int qt   = v >> 3;
    const int oct  = v & 7;

    int base, np;
    if (qt >= 24)      { base = (31 - qt) * 8;        np = 8; }
    else if (qt >= 16) { base = 64  + (23 - qt) * 6;  np = 6; }
    else if (qt >= 8)  { base = 112 + (15 - qt) * 4;  np = 4; }
    else               { base = 144 + (7 - qt) * 2;   np = 2; }

    float* obase = out + ((size_t)b * TT + qt * 64) * HH;

    const int row0 = oct * 8;
    float den[8] = {0,0,0,0,0,0,0,0};
    float acc[8] = {0,0,0,0,0,0,0,0};
    for (int p = 0; p < np; ++p) {
        const int unit = (base + p) * 8 + b;
        float4 d0 = *(const float4*)&ml[(size_t)unit * 64 + row0];
        float4 d1 = *(const float4*)&ml[(size_t)unit * 64 + row0 + 4];
        den[0] += d0.x; den[1] += d0.y; den[2] += d0.z; den[3] += d0.w;
        den[4] += d1.x; den[5] += d1.y; den[6] += d1.z; den[7] += d1.w;
        union { uint4 q; ushort s[8]; } ov;
        ov.q = *(const uint4*)&Opart[(size_t)unit * 4096 + lane * 64 + row0];
        #pragma unroll
        for (int i = 0; i < 8; ++i) acc[i] += bf2f(ov.s[i]);
    }
    #pragma unroll
    for (int i = 0; i < 8; ++i)
        obase[(size_t)(row0 + i) * HH + lane] = acc[i] / den[i];
}

// ---------------------------------------------------------------------------
extern "C" void kernel_launch(void* const* d_in, const int* in_sizes, int n_in,
                              void* d_out, int out_size, void* d_ws, size_t ws_size,
                              hipStream_t stream)
{
    (void)in_sizes; (void)n_in; (void)out_size; (void)ws_size;
    const float* x  = (const float*)d_in[0];
    const float* Wq = (const float*)d_in[1];
    const float* Wk = (const float*)d_in[2];
    const float* Wv = (const float*)d_in[3];
    float* outp = (float*)d_out;

    // ws: WbT 384K | qb 2M | kbS 2M | vS 2M | Opart 10.49M | ml 328K (~17.3 MB)
    char* base = (char*)d_ws;
    ushort* WbT   = (ushort*)(base);
    ushort* qbuf  = (ushort*)(base + 393216);
    ushort* kbS   = qbuf + (size_t)BT * HH;
    ushort* vSb   = kbS + (size_t)BT * HH;
    ushort* Opart = vSb + (size_t)BT * HH;
    float*  ml    = (float*)((char*)Opart + (size_t)1280 * 4096 * 2);

    wprep_kernel<<<dim3(48),   256, 0, stream>>>(Wq, Wk, Wv, WbT);
    qkv_kernel  <<<dim3(512),  256, 0, stream>>>(x, WbT, qbuf, kbS, vSb);
    attn_kernel <<<dim3(1280), 256, 0, stream>>>(qbuf, kbS, vSb, Opart, ml);
    merge_kernel<<<dim3(512),  256, 0, stream>>>(Opart, ml, outp);
}

// Round 10
// 135.983 us; speedup vs baseline: 1.3194x; 1.0482x over previous
//
#include <hip/hip_runtime.h>
#include <hip/hip_bf16.h>
#include <math.h>

#define BB 8
#define TT 2048
#define CC 1024
#define HH 64
#define BT (BB * TT)   // 16384 rows

typedef __attribute__((ext_vector_type(8))) short short8;   // bf16 x8 MFMA frag
typedef __attribute__((ext_vector_type(4))) float floatx4;  // MFMA acc

static __device__ inline ushort f2bf(float f) {
    __hip_bfloat16 h = __float2bfloat16(f);
    return *reinterpret_cast<ushort*>(&h);
}
static __device__ inline unsigned int f2bf2(float lo, float hi) {
    __hip_bfloat162 h = __float22bfloat162_rn(make_float2(lo, hi));
    return *reinterpret_cast<unsigned int*>(&h);
}
static __device__ inline float bf2f(ushort u) {
    union { unsigned int i; float f; } c;
    c.i = ((unsigned int)u) << 16;
    return c.f;
}
// async global->LDS DMA, 16 B per lane; dest = wave-uniform base + lane*16.
static __device__ inline void gl_ldsf(const float* g, float* l) {
    __builtin_amdgcn_global_load_lds(
        (const __attribute__((address_space(1))) unsigned int*)g,
        (__attribute__((address_space(3))) unsigned int*)l,
        16, 0, 0);
}

// ---------------------------------------------------------------------------
// Kernel 0: W prep (coalesced).  W[k][n] fp32 -> WbT[m][n][k] bf16.
// ---------------------------------------------------------------------------
__global__ __launch_bounds__(256) void wprep_kernel(
    const float* __restrict__ Wq, const float* __restrict__ Wk,
    const float* __restrict__ Wv, ushort* __restrict__ WbT)
{
    __shared__ float ws_[64 * 65];
    const int m  = blockIdx.x >> 4;          // 0..2
    const int kb = (blockIdx.x & 15) * 64;   // 0..960
    const float* W = (m == 0) ? Wq : (m == 1) ? Wk : Wv;
    const int t  = threadIdx.x;
    const int lr = t >> 4, lc = (t & 15) * 4;
    #pragma unroll
    for (int i = 0; i < 4; ++i) {
        const int row = lr + i * 16;
        float4 v = *(const float4*)&W[(size_t)(kb + row) * HH + lc];
        ws_[row * 65 + lc + 0] = v.x; ws_[row * 65 + lc + 1] = v.y;
        ws_[row * 65 + lc + 2] = v.z; ws_[row * 65 + lc + 3] = v.w;
    }
    __syncthreads();
    const int n = t & 63, kseg = t >> 6;     // kseg 0..3 -> 16 k each
    union { ushort s[16]; uint4 q[2]; } u;
    #pragma unroll
    for (int j = 0; j < 16; ++j)
        u.s[j] = f2bf(ws_[(kseg * 16 + j) * 65 + n]);
    ushort* dst = &WbT[(size_t)(m * 64 + n) * 1024 + kb + kseg * 16];
    *(uint4*)&dst[0] = u.q[0];
    *(uint4*)&dst[8] = u.q[1];
}

// ---------------------------------------------------------------------------
// Kernel 1: QKV — DMA-ring staging.  x staged fp32 via global_load_lds into a
// ring of 4x8KB LDS buffers; counted s_waitcnt vmcnt(N) per iter (T4) keeps
// 1-2 buffers + W-prefetch in flight ACROSS barriers -> ~28-44 KB/CU in
// flight (Little's-law need ~22 KB), immune to register-prefetch sinking.
// LDS linear for DMA; read-side XOR swizzle byte^=((S&7)<<4) applied as the
// INVERSE permutation on the per-lane GLOBAL source address (m173 pattern).
// W-frags: depth-2 register prefetch (2-iter slack >= L2 latency).
// MFMA order + RN conversions identical to round 5 -> bit-exact outputs.
// ---------------------------------------------------------------------------
__global__ __launch_bounds__(256) void qkv_kernel(
    const float* __restrict__ x, const ushort* __restrict__ WbT,
    ushort* __restrict__ qb, ushort* __restrict__ kbS, ushort* __restrict__ vS)
{
    __shared__ __align__(16) float Xs[4][2048];   // 4 ring buffers x 8 KB fp32

    const int row0 = blockIdx.x * 32;
    const int t    = threadIdx.x;
    const int w    = t >> 6;
    const int lane = t & 63;
    const int l16  = lane & 15;
    const int quad = lane >> 4;
    const int ct0  = w * 3;

    // ---- writer-side global source (inverse of the read-side swizzle) ----
    // physical chunk D = w*128 + j*64 + lane must hold linear chunk
    // C = inv(D): c0=d0^d1^d2^d3, c1=d1^d2^d3, c2=d2^d3, c3=d3 (upper same).
    // Decoded: row = (w&1)*16 + ((lane>>3)&7) + j*8,
    //          kof = (w>>1)*32 + quads*8 + h*4.
    const int d0 = lane & 1, d1 = (lane >> 1) & 1, d2 = (lane >> 2) & 1, d3 = (lane >> 3) & 1;
    const int quads = (d1 ^ d2 ^ d3) + 2 * (d2 ^ d3);
    const int hh    = d0 ^ d1 ^ d2 ^ d3;
    const int kof   = (w >> 1) * 32 + quads * 8 + hh * 4;
    const int rowA  = (w & 1) * 16 + ((lane >> 3) & 7);
    const float* srcA = &x[(size_t)(row0 + rowA) * CC + kof];
    const float* srcB = srcA + (size_t)8 * CC;      // j=1: +8 rows

    // ---- reader-side swizzled byte offsets (frag f=(p*2+mt), half h) ----
    int off[4][2];
    #pragma unroll
    for (int f = 0; f < 4; ++f) {
        const int Sr = f * 64 + l16 * 4 + quad;
        const int sw = (Sr & 7) << 4;
        off[f][0] = (Sr * 32) ^ sw;
        off[f][1] = (Sr * 32 + 16) ^ sw;
    }

    floatx4 acc[2][3];
    #pragma unroll
    for (int mt = 0; mt < 2; ++mt)
        #pragma unroll
        for (int c = 0; c < 3; ++c) acc[mt][c] = (floatx4){0.f, 0.f, 0.f, 0.f};

    // ---- prologue: stage bufs 0..2, then W slots for it0/it1 ----
    #define STAGE(buf, itx) do {                                   \
        gl_ldsf(srcA + (itx) * 64, &Xs[buf][w * 512]);             \
        gl_ldsf(srcB + (itx) * 64, &Xs[buf][w * 512 + 256]);       \
    } while (0)

    STAGE(0, 0); STAGE(1, 1); STAGE(2, 2);
    asm volatile("" ::: "memory");      // pin: W loads stay AFTER the stages

    short8 bW[2][2][3];
    #pragma unroll
    for (int s = 0; s < 2; ++s)
        #pragma unroll
        for (int p = 0; p < 2; ++p)
            #pragma unroll
            for (int c = 0; c < 3; ++c)
                bW[s][p][c] = *(const short8*)&WbT[(size_t)((ct0 + c) * 16 + l16) * 1024
                                                   + s * 64 + p * 32 + quad * 8];

    #pragma unroll
    for (int it = 0; it < 16; ++it) {
        // exact counted waits: ensure buf[it]'s DMA (this wave's part) done.
        if (it == 0)       asm volatile("s_waitcnt vmcnt(16)" ::: "memory");
        else if (it < 14)  asm volatile("s_waitcnt vmcnt(22)" ::: "memory");
        else if (it == 14) asm volatile("s_waitcnt vmcnt(20)" ::: "memory");
        else               asm volatile("s_waitcnt vmcnt(12)" ::: "memory");
        __builtin_amdgcn_s_barrier();   // all waves cleared their part -> buf ready

        if (it + 3 < 16) STAGE((it + 3) & 3, it + 3);
        asm volatile("" ::: "memory");  // pin: W loads below stay AFTER this stage

        // ---- x frags from ring buffer (swizzled b128 reads, fp32->bf16) ----
        const char* bufc = (const char*)&Xs[it & 3][0];
        short8 a[4];
        #pragma unroll
        for (int f = 0; f < 4; ++f) {
            float4 lo = *(const float4*)(bufc + off[f][0]);
            float4 hi = *(const float4*)(bufc + off[f][1]);
            union { unsigned int u[4]; short8 s; } cv;
            cv.u[0] = f2bf2(lo.x, lo.y); cv.u[1] = f2bf2(lo.z, lo.w);
            cv.u[2] = f2bf2(hi.x, hi.y); cv.u[3] = f2bf2(hi.z, hi.w);
            a[f] = cv.s;
        }

        __builtin_amdgcn_s_setprio(1);
        #pragma unroll
        for (int c = 0; c < 3; ++c) {
            acc[0][c] = __builtin_amdgcn_mfma_f32_16x16x32_bf16(a[0], bW[it & 1][0][c], acc[0][c], 0, 0, 0);
            acc[1][c] = __builtin_amdgcn_mfma_f32_16x16x32_bf16(a[1], bW[it & 1][0][c], acc[1][c], 0, 0, 0);
            acc[0][c] = __builtin_amdgcn_mfma_f32_16x16x32_bf16(a[2], bW[it & 1][1][c], acc[0][c], 0, 0, 0);
            acc[1][c] = __builtin_amdgcn_mfma_f32_16x16x32_bf16(a[3], bW[it & 1][1][c], acc[1][c], 0, 0, 0);
        }
        __builtin_amdgcn_s_setprio(0);

        // ---- W depth-2 prefetch: reload this parity slot for it+2 ----
        if (it + 2 < 16) {
            const int kn = (it + 2) * 64;
            #pragma unroll
            for (int p = 0; p < 2; ++p)
                #pragma unroll
                for (int c = 0; c < 3; ++c)
                    bW[it & 1][p][c] = *(const short8*)&WbT[(size_t)((ct0 + c) * 16 + l16) * 1024
                                                            + kn + p * 32 + quad * 8];
        }
    }
    #undef STAGE

    // ---- epilogue (identical to round 5) ----
    const int half = (row0 >> 5) & 1;              // which 32-row half of the 64-tile
    const size_t tile = (size_t)(row0 >> 6) * 4096;
    #pragma unroll
    for (int c = 0; c < 3; ++c) {
        const int ct    = ct0 + c;
        const int mtype = ct >> 2;
        const int n0    = (ct & 3) * 16;
        #pragma unroll
        for (int mt = 0; mt < 2; ++mt) {
            const int row = row0 + mt * 16 + quad * 4;
            if (mtype == 0) {                       // q: row-major, /8 folded
                #pragma unroll
                for (int reg = 0; reg < 4; ++reg)
                    qb[(size_t)(row + reg) * HH + n0 + l16] = f2bf(acc[mt][c][reg] * 0.125f);
            } else if (mtype == 1) {                // K swizzled (B-frag order)
                const int cP    = half * 2 + mt;
                const int pP    = (ct & 3) >> 1;
                const int quadP = ((ct & 3) * 2 + (l16 >> 3)) & 3;
                const int jP    = l16 & 7;
                const int ub    = (cP * 2 + pP) * 64 + quadP * 16;
                #pragma unroll
                for (int reg = 0; reg < 4; ++reg)
                    kbS[tile + (size_t)(ub + quad * 4 + reg) * 8 + jP] = f2bf(acc[mt][c][reg]);
            } else {                                // V swizzled (B-frag order)
                const int cp2 = (ct & 3) * 2 + half;   // c'*2 + p'
                #pragma unroll
                for (int reg = 0; reg < 4; ++reg) {
                    const int rq    = quad * 4 + reg;
                    const int quadP = mt * 2 + (rq >> 3);
                    vS[tile + (size_t)(cp2 * 64 + quadP * 16 + l16) * 8 + (rq & 7)] = f2bf(acc[mt][c][reg]);
                }
            }
        }
    }
}

// ---------------------------------------------------------------------------
// Kernel 2: split-K MFMA flash attention — round-5 version (640 blocks,
// np={4,3,2,1}; barrier-free, swapped QK^T, transposed packed Opart).
// ---------------------------------------------------------------------------
__global__ __launch_bounds__(256) void attn_kernel(
    const ushort* __restrict__ qb, const ushort* __restrict__ kbS,
    const ushort* __restrict__ vS, ushort* __restrict__ Opart,
    float* __restrict__ ml)
{
    __shared__ __align__(16) ushort P[4][16 * 72];   // per-wave P tile

    const int t    = threadIdx.x;
    const int w    = t >> 6;
    const int lane = t & 63;
    const int l16  = lane & 15;
    const int quad = lane >> 4;

    const int b   = blockIdx.x & 7;
    const int idx = blockIdx.x >> 3;   // 0..79, heavy-first
    int qt, part, np;
    if (idx < 32)      { qt = 31 - (idx >> 2); part = idx & 3; np = 4; }
    else if (idx < 56) { const int u = idx - 32; const int g = u / 3;
                         qt = 23 - g; part = u - g * 3; np = 3; }
    else if (idx < 72) { const int u = idx - 56; qt = 15 - (u >> 1); part = u & 1; np = 2; }
    else               { qt = 7 - (idx - 72); part = 0; np = 1; }
    const int ntiles = qt + 1;
    const int ktb = (part * ntiles) / np;
    const int kte = ((part + 1) * ntiles) / np;

    const ushort* ktile0 = kbS + (size_t)(b * 32) * 4096;
    const ushort* vtile0 = vS  + (size_t)(b * 32) * 4096;

    // Q frags (B-operand of swapped QK^T; B-frag lane map == A-frag map)
    short8 qf[2];
    {
        const ushort* qrow = qb + ((size_t)b * TT + qt * 64 + w * 16) * HH;
        qf[0] = *(const short8*)&qrow[l16 * HH + quad * 8];
        qf[1] = *(const short8*)&qrow[l16 * HH + 32 + quad * 8];
    }
    short8 ones;
    #pragma unroll
    for (int i = 0; i < 8; ++i) ones[i] = (short)0x3F80;   // bf16 1.0

    floatx4 o[4], osum;
    #pragma unroll
    for (int c = 0; c < 4; ++c) o[c] = (floatx4){0.f, 0.f, 0.f, 0.f};
    osum = (floatx4){0.f, 0.f, 0.f, 0.f};

    ushort* Pw = &P[w][0];

    for (int kt = ktb; kt < kte; ++kt) {
        const ushort* kg = ktile0 + (size_t)kt * 4096;
        const ushort* vg = vtile0 + (size_t)kt * 4096;

        // ---- K frags from global (L2-hit, frag-ordered) ----
        short8 kf[4][2];
        #pragma unroll
        for (int c = 0; c < 4; ++c)
            #pragma unroll
            for (int p = 0; p < 2; ++p)
                kf[c][p] = *(const short8*)&kg[(size_t)(((c * 2 + p) * 64) + lane) * 8];

        // ---- S^T = K Q^T (operand-swapped): row=key chunk, col=q ----
        floatx4 s[4];
        #pragma unroll
        for (int c = 0; c < 4; ++c) s[c] = (floatx4){0.f, 0.f, 0.f, 0.f};
        __builtin_amdgcn_s_setprio(1);
        #pragma unroll
        for (int c = 0; c < 4; ++c)
            #pragma unroll
            for (int p = 0; p < 2; ++p)
                s[c] = __builtin_amdgcn_mfma_f32_16x16x32_bf16(kf[c][p], qf[p], s[c], 0, 0, 0);
        __builtin_amdgcn_s_setprio(0);

        // ---- V frags (issued while exp/P path runs) ----
        short8 vf[4][2];
        #pragma unroll
        for (int c = 0; c < 4; ++c)
            #pragma unroll
            for (int p = 0; p < 2; ++p)
                vf[c][p] = *(const short8*)&vg[(size_t)(((c * 2 + p) * 64) + lane) * 8];

        // ---- causal mask (roles swapped: key from reg, q from l16) ----
        if (kt == ntiles - 1) {
            const int key0 = kt * 64 + quad * 4;
            const int qrow = qt * 64 + w * 16 + l16;
            #pragma unroll
            for (int c = 0; c < 4; ++c)
                #pragma unroll
                for (int reg = 0; reg < 4; ++reg)
                    if (key0 + c * 16 + reg > qrow) s[c][reg] = -1e30f;
        }

        // ---- P = exp(s^T) -> packed bf16 -> LDS row q=l16, keys contiguous ----
        #pragma unroll
        for (int c = 0; c < 4; ++c) {
            uint2 u;
            u.x = f2bf2(__expf(s[c][0]), __expf(s[c][1]));
            u.y = f2bf2(__expf(s[c][2]), __expf(s[c][3]));
            *(uint2*)&Pw[l16 * 72 + c * 16 + quad * 4] = u;
        }

        short8 pf[2];
        pf[0] = *(const short8*)&Pw[l16 * 72 + quad * 8];
        pf[1] = *(const short8*)&Pw[l16 * 72 + 32 + quad * 8];

        // ---- O += P V ; l += P * ones ----
        __builtin_amdgcn_s_setprio(1);
        #pragma unroll
        for (int p = 0; p < 2; ++p) {
            #pragma unroll
            for (int c = 0; c < 4; ++c)
                o[c] = __builtin_amdgcn_mfma_f32_16x16x32_bf16(pf[p], vf[c][p], o[c], 0, 0, 0);
            osum = __builtin_amdgcn_mfma_f32_16x16x32_bf16(pf[p], ones, osum, 0, 0, 0);
        }
        __builtin_amdgcn_s_setprio(0);
    }

    // ---- write partial TRANSPOSED: Opart[unit][col][row], packed b64 ----
    const size_t ub = (size_t)blockIdx.x * 4096;
    const int rbase = w * 16 + quad * 4;
    #pragma unroll
    for (int c = 0; c < 4; ++c) {
        uint2 u;
        u.x = f2bf2(o[c][0], o[c][1]);
        u.y = f2bf2(o[c][2], o[c][3]);
        *(uint2*)&Opart[ub + (size_t)(c * 16 + l16) * 64 + rbase] = u;
    }
    if (l16 == 0) {
        #pragma unroll
        for (int reg = 0; reg < 4; ++reg)
            ml[(size_t)blockIdx.x * 64 + rbase + reg] = osum[reg];
    }
}

// ---------------------------------------------------------------------------
// Kernel 3: merge partials (transposed Opart, np<=4) — round-5 version.
// ---------------------------------------------------------------------------
__global__ __launch_bounds__(256) void merge_kernel(
    const ushort* __restrict__ Opart, const float* __restrict__ ml,
    float* __restrict__ out)
{
    const int t    = threadIdx.x;
    const int gw   = blockIdx.x * 4 + (t >> 6);   // 0..2047
    const int lane = t & 63;                      // = output col
    const int b    = gw >> 8;
    const int v    = gw & 255;
    const int qt   = v >> 3;
    const int oct  = v & 7;

    int base, np;
    if (qt >= 24)      { base = (31 - qt) * 4;      np = 4; }
    else if (qt >= 16) { base = 32 + (23 - qt) * 3; np = 3; }
    else if (qt >= 8)  { base = 56 + (15 - qt) * 2; np = 2; }
    else               { base = 72 + (7 - qt);      np = 1; }

    float* obase = out + ((size_t)b * TT + qt * 64) * HH;

    #pragma unroll
    for (int rg = 0; rg < 2; ++rg) {
        const int row0 = oct * 8 + rg * 4;
        float dx = 0.f, dy = 0.f, dz = 0.f, dw = 0.f;
        float ax = 0.f, ay = 0.f, az = 0.f, aw = 0.f;
        for (int p = 0; p < np; ++p) {
            const int unit = (base + p) * 8 + b;
            float4 d = *(const float4*)&ml[(size_t)unit * 64 + row0];
            dx += d.x; dy += d.y; dz += d.z; dw += d.w;
            ushort4 ov = *(const ushort4*)&Opart[(size_t)unit * 4096 + lane * 64 + row0];
            ax += bf2f(ov.x); ay += bf2f(ov.y); az += bf2f(ov.z); aw += bf2f(ov.w);
        }
        obase[(size_t)(row0 + 0) * HH + lane] = ax / dx;
        obase[(size_t)(row0 + 1) * HH + lane] = ay / dy;
        obase[(size_t)(row0 + 2) * HH + lane] = az / dz;
        obase[(size_t)(row0 + 3) * HH + lane] = aw / dw;
    }
}

// ---------------------------------------------------------------------------
extern "C" void kernel_launch(void* const* d_in, const int* in_sizes, int n_in,
                              void* d_out, int out_size, void* d_ws, size_t ws_size,
                              hipStream_t stream)
{
    (void)in_sizes; (void)n_in; (void)out_size; (void)ws_size;
    const float* x  = (const float*)d_in[0];
    const float* Wq = (const float*)d_in[1];
    const float* Wk = (const float*)d_in[2];
    const float* Wv = (const float*)d_in[3];
    float* outp = (float*)d_out;

    // ws: WbT 384K | qb 2M | kbS 2M | vS 2M | Opart 5.24M | ml 160K (~11.8 MB)
    char* base = (char*)d_ws;
    ushort* WbT   = (ushort*)(base);
    ushort* qbuf  = (ushort*)(base + 393216);
    ushort* kbS   = qbuf + (size_t)BT * HH;
    ushort* vSb   = kbS + (size_t)BT * HH;
    ushort* Opart = vSb + (size_t)BT * HH;
    float*  ml    = (float*)((char*)Opart + (size_t)640 * 4096 * 2);

    wprep_kernel<<<dim3(48),  256, 0, stream>>>(Wq, Wk, Wv, WbT);
    qkv_kernel  <<<dim3(512), 256, 0, stream>>>(x, WbT, qbuf, kbS, vSb);
    attn_kernel <<<dim3(640), 256, 0, stream>>>(qbuf, kbS, vSb, Opart, ml);
    merge_kernel<<<dim3(512), 256, 0, stream>>>(Opart, ml, outp);
}